// Round 6
// baseline (5127.567 us; speedup 1.0000x reference)
//
#include <hip/hip_runtime.h>
#include <stdint.h>

// Persistent-LSTM, round 5: XCD-local h exchange via the shared per-XCD L2,
// with a sticky agent-scope escalation fallback (can't hang, can't be wrong).
//  - 256 WGs x 128 threads (2 waves), 1 WG/CU (105 KB LDS forces this).
//  - Topology: blocks round-robin across the 8 XCDs (documented dispatch
//    behavior, same assumption as the verified XCD-swizzle technique), so
//    g = bid & 7 selects the row slab (batch rows 8g..8g+7) and all 32 WGs
//    of slab g are co-located on one XCD. m = bid >> 3 owns u-cols
//    16m..16m+15 (64 z-cols = 4 nt tiles). Coverage is by construction;
//    only locality depends on the mapping.
//  - h element = u32 ((t+1)<<16 | bf16(h)) in a parity double buffer.
//    Producer stores sc1 (agent: lands at IF$, updates/invalidates any
//    local-L2 copy). Consumer loads sc0 (bypass L1, serve from the
//    XCD-shared coherent L2: ~250 cy instead of ~1 us at IF$).
//  - Escalation: if a step's poll exceeds 512 retries, the WG PERMANENTLY
//    switches its h loads to sc1 (round-4 proven path). Wrong mapping or
//    store semantics -> round-4 performance, never a hang.
//  - 2-buffer safety: a tag-(t+2) write requires full h_{t+1}, which requires
//    every WG to have consumed step t -> no WAR race. Zeroed hbuf is the
//    valid tag-0 h_0 = 0 state.
//  - Weights staged once to LDS in MFMA B-frag order (96 KB); x-part weight
//    frags in VGPRs. Waves split K by parity; partial z reduced through a
//    small LDS zbuf (2 intra-WG barriers per step).

#define Tt   1024
#define Ff   256
#define Uu   512
#define G4U  2048
#define NWG  256
#define NTHR 128
#define ESC_LIMIT 512

#define WF_ELEMS (4 * 24 * 64 * 8)                  // 49152 bf16 = 96 KB
#define WF_BYTES (WF_ELEMS * 2)
#define ZB_BYTES (2 * 4 * 16 * 17 * 4)              // 8704 B
#define SMEM_BYTES (WF_BYTES + ZB_BYTES)

typedef short  bf16x8 __attribute__((ext_vector_type(8)));
typedef float  f32x4  __attribute__((ext_vector_type(4)));
typedef int    int4v  __attribute__((ext_vector_type(4)));
typedef unsigned int u32;

__device__ __forceinline__ unsigned short f2bf(float f) {
  u32 u = __builtin_bit_cast(u32, f);
  u += 0x7fffu + ((u >> 16) & 1u);                  // RNE (finite inputs)
  return (unsigned short)(u >> 16);
}
__device__ __forceinline__ u32 umin32(u32 a, u32 b) { return a < b ? a : b; }

// sc0: bypass per-CU L1, serve from the XCD-shared (coherent) L2.
__device__ __forceinline__ int4v load16_l2(const u32* p) {
  int4v r;
  asm volatile("global_load_dwordx4 %0, %1, off sc0"
               : "=v"(r) : "v"(p) : "memory");
  return r;
}
// sc1: agent scope -- bypass L1 + non-coherent L2, serve at IF$ (round-4 path).
__device__ __forceinline__ int4v load16_ag(const u32* p) {
  int4v r;
  asm volatile("global_load_dwordx4 %0, %1, off sc1"
               : "=v"(r) : "v"(p) : "memory");
  return r;
}
// Producer store: agent scope (visible at IF$; local L2 copy updated or
// invalidated by the write-through -- either way no stale local copy).
__device__ __forceinline__ void store4_ag(u32* p, u32 v) {
  asm volatile("global_store_dword %0, %1, off sc1"
               :: "v"(p), "v"(v) : "memory");
}

__device__ __forceinline__ float sigf(float z) {
  return __builtin_amdgcn_rcpf(1.f + __expf(-z));
}
__device__ __forceinline__ float tanh_fast(float v) {
  const float e = __expf(-2.f * fabsf(v));
  const float r = (1.f - e) * __builtin_amdgcn_rcpf(1.f + e);
  return copysignf(r, v);
}

extern "C" __global__ void __launch_bounds__(NTHR, 1)
lstm_persistent(const float* __restrict__ x,
                const float* __restrict__ Wk,
                const float* __restrict__ Rk,
                const float* __restrict__ bias,
                float* __restrict__ out,
                u32* __restrict__ hbuf)             // [2][64][512] tagged u32
{
  extern __shared__ char smem[];
  unsigned short* wf   = (unsigned short*)smem;            // [nt4][kt24][64][8]
  float*          zbuf = (float*)(smem + WF_BYTES);        // [w][nt][16][17]

  const int bid = blockIdx.x;
  const int tid = threadIdx.x;
  const int w   = tid >> 6;
  const int l   = tid & 63;
  const int g   = bid & 7;         // row slab: batch rows 8g..8g+7 (XCD-local)
  const int m   = bid >> 3;        // 0..31: u-cols 16m..16m+15

  // ---- one-time weight staging into MFMA B-fragment order ----
  // local col (nt, nn) -> global z-col  zc = nt*512 + m*16 + nn  (nt = gate)
  for (int i = tid; i < WF_ELEMS; i += NTHR) {
    const int j    = i & 7;
    const int lane = (i >> 3) & 63;
    const int kt   = (i >> 9) % 24;
    const int nt   = (i >> 9) / 24;
    const int k    = kt * 32 + ((lane >> 4) << 3) + j;     // 0..767
    const int zc   = nt * Uu + m * 16 + (lane & 15);
    const float v  = (k < Ff) ? Wk[(size_t)k * G4U + zc]
                              : Rk[(size_t)(k - Ff) * G4U + zc];
    wf[i] = f2bf(v);
  }
  __syncthreads();

  // ---- preload x-part weight fragments (kt = 2q+w, q=0..3; 64 VGPR) ----
  bf16x8 wfx[4][4];
  #pragma unroll
  for (int q = 0; q < 4; ++q)
    #pragma unroll
    for (int nt = 0; nt < 4; ++nt)
      wfx[q][nt] = *(const bf16x8*)(wf + ((nt * 24 + (2 * q + w)) * 64 + l) * 8);

  // ---- combine-role constants: 128 threads = 8 rows x 16 u ----
  const int r_c   = tid >> 4;                 // 0..7
  const int uu    = tid & 15;
  const int b_out = g * 8 + r_c;
  const int u_out = m * 16 + uu;
  float breg[4];
  #pragma unroll
  for (int gg = 0; gg < 4; ++gg) breg[gg] = bias[gg * Uu + u_out];
  float creg = 0.f;

  // ---- load-role constants (MFMA A-frag; rows 8..15 alias 0..7) ----
  const int b_ld = g * 8 + (l & 7);
  const int kq   = (l >> 4) * 8;

  int esc = 0;                                // sticky escalation flag

  for (int t = 0; t < Tt; ++t) {
    // ---- issue h loads first (L2-local fast path, or escalated) ----
    const u32* hp = hbuf + ((size_t)(t & 1) * 64 + b_ld) * Uu + kq;
    int4v hf[16];
    if (!esc) {
      #pragma unroll
      for (int q = 0; q < 8; ++q) {
        hf[2 * q]     = load16_l2(hp + (2 * q + w) * 32);
        hf[2 * q + 1] = load16_l2(hp + (2 * q + w) * 32 + 4);
      }
    } else {
      #pragma unroll
      for (int q = 0; q < 8; ++q) {
        hf[2 * q]     = load16_ag(hp + (2 * q + w) * 32);
        hf[2 * q + 1] = load16_ag(hp + (2 * q + w) * 32 + 4);
      }
    }

    // ---- x phase: fp32 loads + cvt + 16 MFMAs (kt = 2q+w, 4 nt) ----
    f32x4 aX[4] = {{0,0,0,0},{0,0,0,0},{0,0,0,0},{0,0,0,0}};
    const float* xp = x + ((size_t)b_ld * Tt + t) * Ff + kq;
    #pragma unroll
    for (int q = 0; q < 4; ++q) {
      const int kt = 2 * q + w;
      const float4 v0 = *(const float4*)(xp + kt * 32);
      const float4 v1 = *(const float4*)(xp + kt * 32 + 4);
      int r0, r1, r2, r3;
      asm("v_cvt_pk_bf16_f32 %0, %1, %2" : "=v"(r0) : "v"(v0.x), "v"(v0.y));
      asm("v_cvt_pk_bf16_f32 %0, %1, %2" : "=v"(r1) : "v"(v0.z), "v"(v0.w));
      asm("v_cvt_pk_bf16_f32 %0, %1, %2" : "=v"(r2) : "v"(v1.x), "v"(v1.y));
      asm("v_cvt_pk_bf16_f32 %0, %1, %2" : "=v"(r3) : "v"(v1.z), "v"(v1.w));
      const int4v ai = {r0, r1, r2, r3};
      const bf16x8 a = __builtin_bit_cast(bf16x8, ai);
      #pragma unroll
      for (int nt = 0; nt < 4; ++nt)
        aX[nt] = __builtin_amdgcn_mfma_f32_16x16x32_bf16(a, wfx[q][nt], aX[nt], 0, 0, 0);
    }

    // ---- h poll: validate embedded tags only; escalate if stuck ----
    int tries = 0;
    for (;;) {
      asm volatile("s_waitcnt vmcnt(0)" ::: "memory");
      __builtin_amdgcn_sched_barrier(0);
      u32 m0 = ~0u, m1 = ~0u, m2 = ~0u, m3 = ~0u;
      #pragma unroll
      for (int q = 0; q < 16; ++q) {
        m0 = umin32(m0, (u32)hf[q][0]);
        m1 = umin32(m1, (u32)hf[q][1]);
        m2 = umin32(m2, (u32)hf[q][2]);
        m3 = umin32(m3, (u32)hf[q][3]);
      }
      const u32 mv = umin32(umin32(m0, m1), umin32(m2, m3));
      if (__all((mv >> 16) == (u32)t)) break;       // all tags fresh
      if (++tries > ESC_LIMIT) esc = 1;             // sticky fallback
      __builtin_amdgcn_s_sleep(1);
      if (!esc) {
        #pragma unroll
        for (int q = 0; q < 8; ++q) {
          hf[2 * q]     = load16_l2(hp + (2 * q + w) * 32);
          hf[2 * q + 1] = load16_l2(hp + (2 * q + w) * 32 + 4);
        }
      } else {
        #pragma unroll
        for (int q = 0; q < 8; ++q) {
          hf[2 * q]     = load16_ag(hp + (2 * q + w) * 32);
          hf[2 * q + 1] = load16_ag(hp + (2 * q + w) * 32 + 4);
        }
      }
    }

    // ---- h phase: repack + 32 MFMAs, once, on validated data ----
    f32x4 aH[4] = {{0,0,0,0},{0,0,0,0},{0,0,0,0},{0,0,0,0}};
    #pragma unroll
    for (int q = 0; q < 8; ++q) {
      const int kt = 8 + 2 * q + w;
      const u32 w0 = __builtin_amdgcn_perm((u32)hf[2*q][1],   (u32)hf[2*q][0],   0x05040100u);
      const u32 w1 = __builtin_amdgcn_perm((u32)hf[2*q][3],   (u32)hf[2*q][2],   0x05040100u);
      const u32 w2 = __builtin_amdgcn_perm((u32)hf[2*q+1][1], (u32)hf[2*q+1][0], 0x05040100u);
      const u32 w3 = __builtin_amdgcn_perm((u32)hf[2*q+1][3], (u32)hf[2*q+1][2], 0x05040100u);
      const int4v ai = {(int)w0, (int)w1, (int)w2, (int)w3};
      const bf16x8 a = __builtin_bit_cast(bf16x8, ai);
      #pragma unroll
      for (int nt = 0; nt < 4; ++nt) {
        const bf16x8 b = *(const bf16x8*)(wf + ((nt * 24 + kt) * 64 + l) * 8);
        aH[nt] = __builtin_amdgcn_mfma_f32_16x16x32_bf16(a, b, aH[nt], 0, 0, 0);
      }
    }

    // ---- cross-wave z reduce through zbuf ----
    __syncthreads();                                // WAR vs previous combine
    {
      const int col = l & 15, rb = (l >> 4) * 4;
      #pragma unroll
      for (int nt = 0; nt < 4; ++nt) {
        #pragma unroll
        for (int i = 0; i < 4; ++i)
          zbuf[((w * 4 + nt) * 16 + rb + i) * 17 + col] = aX[nt][i] + aH[nt][i];
      }
    }
    __syncthreads();

    // ---- gate math (fp32), cell update; h store FIRST (critical path) ----
    float z[4];
    #pragma unroll
    for (int gg = 0; gg < 4; ++gg)
      z[gg] = zbuf[((0 * 4 + gg) * 16 + r_c) * 17 + uu]
            + zbuf[((1 * 4 + gg) * 16 + r_c) * 17 + uu]
            + breg[gg];
    const float ig = sigf(z[0]);
    const float fg = sigf(z[1]);
    const float og = sigf(z[3]);
    const float cc = fg * creg + ig * z[2];
    creg = cc;
    const float hh = og * cc;
    const u32 hw = ((u32)(t + 1) << 16) | (u32)f2bf(hh);
    store4_ag(hbuf + ((size_t)((t + 1) & 1) * 64 + b_out) * Uu + u_out, hw);
    out[((size_t)b_out * Tt + t) * Uu + u_out] = tanh_fast(hh);
  }
}

extern "C" void kernel_launch(void* const* d_in, const int* in_sizes, int n_in,
                              void* d_out, int out_size, void* d_ws, size_t ws_size,
                              hipStream_t stream) {
  const float* x    = (const float*)d_in[0];
  const float* Wk   = (const float*)d_in[1];
  const float* Rk   = (const float*)d_in[2];
  const float* bias = (const float*)d_in[3];
  float* out = (float*)d_out;
  u32* hbuf = (u32*)d_ws;

  // zeroed hbuf == valid tag-0 h_0 = 0 for both parities.
  hipMemsetAsync(d_ws, 0, (size_t)2 * 64 * Uu * sizeof(u32), stream);

  (void)hipFuncSetAttribute((const void*)lstm_persistent,
                            hipFuncAttributeMaxDynamicSharedMemorySize,
                            SMEM_BYTES);

  hipLaunchKernelGGL(lstm_persistent, dim3(NWG), dim3(NTHR), SMEM_BYTES, stream,
                     x, Wk, Rk, bias, out, hbuf);
}